// Round 1
// baseline (35865.829 us; speedup 1.0000x reference)
//
#include <hip/hip_runtime.h>
#include <hip/hip_bf16.h>
#include <math.h>

#define BSZ 512
#define TT 100
#define ND 10
#define DS 6
#define INW 256
#define HW 256
#define SAW 2816
#define G4 1024

// ---------------------------------------------------------------------------
// Generic f32 tiled GEMM: C[M,N] = act(A[M,K] . B[N,K]^T + bias[N])
// 64x64 tile, 256 threads, 4x4 per-thread microtile, K-tile 16.
// All M,N,K here are multiples of 64/16 so no bounds checks.
// ---------------------------------------------------------------------------
template<bool RELU>
__global__ __launch_bounds__(256) void gemm64(const float* __restrict__ A, int lda,
                                              const float* __restrict__ B, int ldb,
                                              const float* __restrict__ bias,
                                              float* __restrict__ C, int ldc, int K)
{
    __shared__ float As[16][68];
    __shared__ float Bs[16][68];
    const int tid = threadIdx.x;
    const int ty = tid >> 4, tx = tid & 15;
    const int m0 = blockIdx.x * 64, n0 = blockIdx.y * 64;
    const int row = tid >> 2;            // 0..63
    const int kq  = (tid & 3) << 2;      // 0,4,8,12

    float acc[4][4];
#pragma unroll
    for (int i = 0; i < 4; ++i)
#pragma unroll
        for (int j = 0; j < 4; ++j) acc[i][j] = 0.f;

    const float* Ap = A + (size_t)(m0 + row) * lda + kq;
    const float* Bp = B + (size_t)(n0 + row) * ldb + kq;

    for (int kt = 0; kt < K; kt += 16) {
        float4 av = *(const float4*)(Ap + kt);
        float4 bv = *(const float4*)(Bp + kt);
        As[kq + 0][row] = av.x; As[kq + 1][row] = av.y;
        As[kq + 2][row] = av.z; As[kq + 3][row] = av.w;
        Bs[kq + 0][row] = bv.x; Bs[kq + 1][row] = bv.y;
        Bs[kq + 2][row] = bv.z; Bs[kq + 3][row] = bv.w;
        __syncthreads();
#pragma unroll
        for (int kk = 0; kk < 16; ++kk) {
            float a[4], b[4];
#pragma unroll
            for (int i = 0; i < 4; ++i) a[i] = As[kk][ty * 4 + i];
#pragma unroll
            for (int j = 0; j < 4; ++j) b[j] = Bs[kk][tx * 4 + j];
#pragma unroll
            for (int i = 0; i < 4; ++i)
#pragma unroll
                for (int j = 0; j < 4; ++j) acc[i][j] += a[i] * b[j];
        }
        __syncthreads();
    }

#pragma unroll
    for (int i = 0; i < 4; ++i) {
        const int m = m0 + ty * 4 + i;
#pragma unroll
        for (int j = 0; j < 4; ++j) {
            const int n = n0 + tx * 4 + j;
            float v = acc[i][j] + bias[n];
            if (RELU) v = v > 0.f ? v : 0.f;
            C[(size_t)m * ldc + n] = v;
        }
    }
}

// ---------------------------------------------------------------------------
// Build concatenated LSTM weight [1024][512] = [W_ih | W_hh] and bias sum.
// ---------------------------------------------------------------------------
__global__ void build_wcat(const float* __restrict__ W_ih, const float* __restrict__ W_hh,
                           const float* __restrict__ b_ih, const float* __restrict__ b_hh,
                           float* __restrict__ wcat, float* __restrict__ bcat)
{
    const int j = blockIdx.x;       // 0..1023
    const int k = threadIdx.x;      // 0..255
    wcat[j * 512 + k]       = W_ih[j * 256 + k];
    wcat[j * 512 + 256 + k] = W_hh[j * 256 + k];
    if (k == 0) bcat[j] = b_ih[j] + b_hh[j];
}

// ---------------------------------------------------------------------------
// LSTM elementwise: consume gates[512][1024], update c; write h into
// zbuf[:,256:512] (carry) and xbuf[:,2560:2816] (MLP input tail).
// ---------------------------------------------------------------------------
__global__ __launch_bounds__(256) void lstm_elem(const float* __restrict__ gates,
                                                 float* __restrict__ cbuf,
                                                 float* __restrict__ zbuf,
                                                 float* __restrict__ xbuf)
{
    const int b = blockIdx.x, k = threadIdx.x;
    const float gi = gates[b * 1024 + k];
    const float gf = gates[b * 1024 + 256 + k];
    const float gg = gates[b * 1024 + 512 + k];
    const float go = gates[b * 1024 + 768 + k];
    const float si = 1.f / (1.f + expf(-gi));
    const float sf = 1.f / (1.f + expf(-gf));
    const float so = 1.f / (1.f + expf(-go));
    float cv = cbuf[b * 256 + k];
    cv = sf * cv + si * tanhf(gg);
    const float hv = so * tanhf(cv);
    cbuf[b * 256 + k] = cv;
    zbuf[b * 512 + 256 + k] = hv;
    xbuf[b * SAW + 2560 + k] = hv;
}

// ---------------------------------------------------------------------------
// emb: xbuf[b, n*256+i] = bd[i] + sum_d desc[b,t,n,d] * Wd[i,d]
// ---------------------------------------------------------------------------
__global__ __launch_bounds__(256) void emb_kernel(const float* __restrict__ desc,
                                                  const float* __restrict__ Wd,
                                                  const float* __restrict__ bd,
                                                  float* __restrict__ xbuf, int t)
{
    __shared__ float sd[60];
    __shared__ float swd[1536];
    const int b = blockIdx.x, tid = threadIdx.x;
    if (tid < 60) sd[tid] = desc[(size_t)b * (TT * ND * DS) + t * (ND * DS) + tid];
    for (int i = tid; i < 1536; i += 256) swd[i] = Wd[i];
    __syncthreads();
    const float bdv = bd[tid];
#pragma unroll
    for (int n = 0; n < ND; ++n) {
        float acc = bdv;
#pragma unroll
        for (int d = 0; d < DS; ++d) acc += sd[n * DS + d] * swd[tid * DS + d];
        xbuf[(size_t)b * SAW + n * 256 + tid] = acc;
    }
}

// ---------------------------------------------------------------------------
// a[b,n] = y[b,:] . Wv[n,:] + bv[n]  -> out[b,t,n]   (N=10, K=2816)
// ---------------------------------------------------------------------------
__global__ __launch_bounds__(256) void av_kernel(const float* __restrict__ y,
                                                 const float* __restrict__ Wv,
                                                 const float* __restrict__ bv,
                                                 float* __restrict__ out, int t)
{
    __shared__ float ys[SAW];
    __shared__ float red[ND][4];
    const int b = blockIdx.x, tid = threadIdx.x;
    for (int i = tid; i < SAW; i += 256) ys[i] = y[(size_t)b * SAW + i];
    __syncthreads();

    float pacc[ND];
#pragma unroll
    for (int n = 0; n < ND; ++n) pacc[n] = 0.f;
    for (int k = tid; k < SAW; k += 256) {
        const float yv = ys[k];
#pragma unroll
        for (int n = 0; n < ND; ++n) pacc[n] += yv * Wv[n * SAW + k];
    }
    const int lane = tid & 63, wid = tid >> 6;
#pragma unroll
    for (int n = 0; n < ND; ++n) {
        float v = pacc[n];
        for (int off = 32; off > 0; off >>= 1) v += __shfl_down(v, off, 64);
        if (lane == 0) red[n][wid] = v;
    }
    __syncthreads();
    if (tid < ND) {
        const float s = red[tid][0] + red[tid][1] + red[tid][2] + red[tid][3] + bv[tid];
        out[(size_t)b * (TT * ND) + t * ND + tid] = s;
    }
}

// ---------------------------------------------------------------------------
extern "C" void kernel_launch(void* const* d_in, const int* in_sizes, int n_in,
                              void* d_out, int out_size, void* d_ws, size_t ws_size,
                              hipStream_t stream)
{
    const float* desc = (const float*)d_in[0];
    const float* Wd   = (const float*)d_in[1];
    const float* bd   = (const float*)d_in[2];
    const float* W1   = (const float*)d_in[3];
    const float* b1   = (const float*)d_in[4];
    const float* W2   = (const float*)d_in[5];
    const float* b2   = (const float*)d_in[6];
    const float* Wv   = (const float*)d_in[7];
    const float* bv   = (const float*)d_in[8];
    const float* W_ih = (const float*)d_in[9];
    const float* W_hh = (const float*)d_in[10];
    const float* b_ih = (const float*)d_in[11];
    const float* b_hh = (const float*)d_in[12];
    float* out = (float*)d_out;

    char* ws = (char*)d_ws;
    float* zbuf  = (float*)(ws);               // [512][512]  = [inp | h]
    float* cbuf  = (float*)(ws + 1048576);     // [512][256]
    float* xbuf  = (float*)(ws + 1572864);     // [512][2816]
    float* ybuf  = (float*)(ws + 7340032);     // [512][2816]
    float* gates = (float*)(ws + 13107200);    // [512][1024]
    float* wcat  = (float*)(ws + 15204352);    // [1024][512]
    float* bcat  = (float*)(ws + 17301504);    // [1024]

    // zero carry state (zbuf + cbuf are contiguous: 1MB + 512KB)
    hipMemsetAsync(ws, 0, 1572864, stream);
    build_wcat<<<dim3(1024), dim3(256), 0, stream>>>(W_ih, W_hh, b_ih, b_hh, wcat, bcat);

    for (int t = 0; t < TT; ++t) {
        // gates = [inp|h] . wcat^T + (b_ih+b_hh)      M=512 N=1024 K=512
        gemm64<false><<<dim3(8, 16), dim3(256), 0, stream>>>(zbuf, 512, wcat, 512, bcat,
                                                             gates, 1024, 512);
        lstm_elem<<<dim3(512), dim3(256), 0, stream>>>(gates, cbuf, zbuf, xbuf);
        emb_kernel<<<dim3(512), dim3(256), 0, stream>>>(desc, Wd, bd, xbuf, t);
        // y = relu(x . W1^T + b1)                     M=512 N=2816 K=2816
        gemm64<true><<<dim3(8, 44), dim3(256), 0, stream>>>(xbuf, SAW, W1, SAW, b1,
                                                            ybuf, SAW, SAW);
        // nxt = relu(y . W2^T + b2) -> zbuf[:,0:256]  M=512 N=256 K=2816
        gemm64<true><<<dim3(8, 4), dim3(256), 0, stream>>>(ybuf, SAW, W2, SAW, b2,
                                                           zbuf, 512, SAW);
        av_kernel<<<dim3(512), dim3(256), 0, stream>>>(ybuf, Wv, bv, out, t);
    }
}

// Round 3
// 27110.654 us; speedup vs baseline: 1.3229x; 1.3229x over previous
//
#include <hip/hip_runtime.h>
#include <hip/hip_bf16.h>
#include <math.h>

#define BSZ 512
#define TT 100
#define ND 10
#define DS 6
#define SAW 2816

typedef _Float16 half8 __attribute__((ext_vector_type(8)));
typedef float floatx4 __attribute__((ext_vector_type(4)));

// ---------------------------------------------------------------------------
// f32 tiled GEMM: C[M,N] = act(A[M,K] . B[N,K]^T + bias[N])  (gates, W2)
// ---------------------------------------------------------------------------
template<bool RELU>
__global__ __launch_bounds__(256) void gemm64(const float* __restrict__ A, int lda,
                                              const float* __restrict__ B, int ldb,
                                              const float* __restrict__ bias,
                                              float* __restrict__ C, int ldc, int K)
{
    __shared__ float As[16][68];
    __shared__ float Bs[16][68];
    const int tid = threadIdx.x;
    const int ty = tid >> 4, tx = tid & 15;
    const int m0 = blockIdx.x * 64, n0 = blockIdx.y * 64;
    const int row = tid >> 2;
    const int kq  = (tid & 3) << 2;

    float acc[4][4];
#pragma unroll
    for (int i = 0; i < 4; ++i)
#pragma unroll
        for (int j = 0; j < 4; ++j) acc[i][j] = 0.f;

    const float* Ap = A + (size_t)(m0 + row) * lda + kq;
    const float* Bp = B + (size_t)(n0 + row) * ldb + kq;

    for (int kt = 0; kt < K; kt += 16) {
        float4 av = *(const float4*)(Ap + kt);
        float4 bv = *(const float4*)(Bp + kt);
        As[kq + 0][row] = av.x; As[kq + 1][row] = av.y;
        As[kq + 2][row] = av.z; As[kq + 3][row] = av.w;
        Bs[kq + 0][row] = bv.x; Bs[kq + 1][row] = bv.y;
        Bs[kq + 2][row] = bv.z; Bs[kq + 3][row] = bv.w;
        __syncthreads();
#pragma unroll
        for (int kk = 0; kk < 16; ++kk) {
            float a[4], b[4];
#pragma unroll
            for (int i = 0; i < 4; ++i) a[i] = As[kk][ty * 4 + i];
#pragma unroll
            for (int j = 0; j < 4; ++j) b[j] = Bs[kk][tx * 4 + j];
#pragma unroll
            for (int i = 0; i < 4; ++i)
#pragma unroll
                for (int j = 0; j < 4; ++j) acc[i][j] += a[i] * b[j];
        }
        __syncthreads();
    }

#pragma unroll
    for (int i = 0; i < 4; ++i) {
        const int m = m0 + ty * 4 + i;
#pragma unroll
        for (int j = 0; j < 4; ++j) {
            const int n = n0 + tx * 4 + j;
            float v = acc[i][j] + bias[n];
            if (RELU) v = v > 0.f ? v : 0.f;
            C[(size_t)m * ldc + n] = v;
        }
    }
}

// ---------------------------------------------------------------------------
// MFMA fp16 3-product split GEMM: C = relu(A.B^T + bias)
// A given as hi/lo f16 planes [M][K], B as hi/lo f16 planes [N][K].
// 64x64 tile per 1-wave block; 4x4 frags of mfma_f32_16x16x32_f16; BK=32.
// LDS row stride 40 f16 (80B = 16*odd -> uniform bank slots, no conflicts).
// ---------------------------------------------------------------------------
__global__ __launch_bounds__(64) void gemm_mfma3_relu(
    const _Float16* __restrict__ Ahi, const _Float16* __restrict__ Alo, int lda,
    const _Float16* __restrict__ Bhi, const _Float16* __restrict__ Blo, int ldb,
    const float* __restrict__ bias, float* __restrict__ C, int ldc, int K)
{
    __shared__ alignas(16) _Float16 sAh[64 * 40];
    __shared__ alignas(16) _Float16 sAl[64 * 40];
    __shared__ alignas(16) _Float16 sBh[64 * 40];
    __shared__ alignas(16) _Float16 sBl[64 * 40];
    const int l = threadIdx.x;
    const int m0 = blockIdx.x * 64, n0 = blockIdx.y * 64;
    const int srow = l >> 2;              // staging row base (0..15), +16*i
    const int sslot = (l & 3) * 8;        // 8-f16 (16B) slot within BK=32
    const int frow = l & 15, fk = (l >> 4) * 8;

    floatx4 acc[4][4];
    const floatx4 z = {0.f, 0.f, 0.f, 0.f};
#pragma unroll
    for (int i = 0; i < 4; ++i)
#pragma unroll
        for (int j = 0; j < 4; ++j) acc[i][j] = z;

    for (int kt = 0; kt < K; kt += 32) {
        // stage 4 planes: 64 rows x 32 f16 each
#pragma unroll
        for (int i = 0; i < 4; ++i) {
            const int r = srow + 16 * i;
            const size_t ga = (size_t)(m0 + r) * lda + kt + sslot;
            const size_t gb = (size_t)(n0 + r) * ldb + kt + sslot;
            const int lo = r * 40 + sslot;
            *(half8*)&sAh[lo] = *(const half8*)(Ahi + ga);
            *(half8*)&sAl[lo] = *(const half8*)(Alo + ga);
            *(half8*)&sBh[lo] = *(const half8*)(Bhi + gb);
            *(half8*)&sBl[lo] = *(const half8*)(Blo + gb);
        }
        __syncthreads();

        half8 ah[4], al[4], bh[4], bl[4];
#pragma unroll
        for (int f = 0; f < 4; ++f) {
            const int ro = (16 * f + frow) * 40 + fk;
            ah[f] = *(const half8*)&sAh[ro];
            al[f] = *(const half8*)&sAl[ro];
            bh[f] = *(const half8*)&sBh[ro];
            bl[f] = *(const half8*)&sBl[ro];
        }
        // three product passes, 16-apart acc reuse distance (no MFMA stalls)
#pragma unroll
        for (int mf = 0; mf < 4; ++mf)
#pragma unroll
            for (int nf = 0; nf < 4; ++nf)
                acc[mf][nf] = __builtin_amdgcn_mfma_f32_16x16x32_f16(ah[mf], bh[nf], acc[mf][nf], 0, 0, 0);
#pragma unroll
        for (int mf = 0; mf < 4; ++mf)
#pragma unroll
            for (int nf = 0; nf < 4; ++nf)
                acc[mf][nf] = __builtin_amdgcn_mfma_f32_16x16x32_f16(ah[mf], bl[nf], acc[mf][nf], 0, 0, 0);
#pragma unroll
        for (int mf = 0; mf < 4; ++mf)
#pragma unroll
            for (int nf = 0; nf < 4; ++nf)
                acc[mf][nf] = __builtin_amdgcn_mfma_f32_16x16x32_f16(al[mf], bh[nf], acc[mf][nf], 0, 0, 0);
        __syncthreads();
    }

    // C/D layout (m89-verified): col = l&15, row = 4*(l>>4) + reg
    const int crow = (l >> 4) * 4, ccol = l & 15;
#pragma unroll
    for (int nf = 0; nf < 4; ++nf) {
        const int col = n0 + 16 * nf + ccol;
        const float bv = bias[col];
#pragma unroll
        for (int mf = 0; mf < 4; ++mf) {
            const int row = m0 + 16 * mf + crow;
#pragma unroll
            for (int j = 0; j < 4; ++j) {
                float v = acc[mf][nf][j] + bv;
                v = v > 0.f ? v : 0.f;
                C[(size_t)(row + j) * ldc + col] = v;
            }
        }
    }
}

// ---------------------------------------------------------------------------
// f32 -> (hi, lo) fp16 split, elementwise
// ---------------------------------------------------------------------------
__global__ __launch_bounds__(256) void cvt_hilo(const float* __restrict__ src,
                                                _Float16* __restrict__ hi,
                                                _Float16* __restrict__ lo, int n)
{
    int i = blockIdx.x * 256 + threadIdx.x;
    const int stride = gridDim.x * 256;
    for (; i < n; i += stride) {
        const float v = src[i];
        const _Float16 h = (_Float16)v;
        hi[i] = h;
        lo[i] = (_Float16)(v - (float)h);
    }
}

// ---------------------------------------------------------------------------
// Build concatenated LSTM weight [1024][512] = [W_ih | W_hh] and bias sum.
// ---------------------------------------------------------------------------
__global__ void build_wcat(const float* __restrict__ W_ih, const float* __restrict__ W_hh,
                           const float* __restrict__ b_ih, const float* __restrict__ b_hh,
                           float* __restrict__ wcat, float* __restrict__ bcat)
{
    const int j = blockIdx.x;
    const int k = threadIdx.x;
    wcat[j * 512 + k]       = W_ih[j * 256 + k];
    wcat[j * 512 + 256 + k] = W_hh[j * 256 + k];
    if (k == 0) bcat[j] = b_ih[j] + b_hh[j];
}

// ---------------------------------------------------------------------------
// LSTM elementwise: update c; h -> zbuf[:,256:512] (f32 carry) and
// xhi/xlo[:,2560:2816] (fp16 split MLP input tail).
// ---------------------------------------------------------------------------
__global__ __launch_bounds__(256) void lstm_elem(const float* __restrict__ gates,
                                                 float* __restrict__ cbuf,
                                                 float* __restrict__ zbuf,
                                                 _Float16* __restrict__ xhi,
                                                 _Float16* __restrict__ xlo)
{
    const int b = blockIdx.x, k = threadIdx.x;
    const float gi = gates[b * 1024 + k];
    const float gf = gates[b * 1024 + 256 + k];
    const float gg = gates[b * 1024 + 512 + k];
    const float go = gates[b * 1024 + 768 + k];
    const float si = 1.f / (1.f + expf(-gi));
    const float sf = 1.f / (1.f + expf(-gf));
    const float so = 1.f / (1.f + expf(-go));
    float cv = cbuf[b * 256 + k];
    cv = sf * cv + si * tanhf(gg);
    const float hv = so * tanhf(cv);
    cbuf[b * 256 + k] = cv;
    zbuf[b * 512 + 256 + k] = hv;
    const _Float16 h = (_Float16)hv;
    xhi[(size_t)b * SAW + 2560 + k] = h;
    xlo[(size_t)b * SAW + 2560 + k] = (_Float16)(hv - (float)h);
}

// ---------------------------------------------------------------------------
// emb: x[b, n*256+i] = bd[i] + sum_d desc[b,t,n,d]*Wd[i,d]  -> fp16 hi/lo
// ---------------------------------------------------------------------------
__global__ __launch_bounds__(256) void emb_kernel(const float* __restrict__ desc,
                                                  const float* __restrict__ Wd,
                                                  const float* __restrict__ bd,
                                                  _Float16* __restrict__ xhi,
                                                  _Float16* __restrict__ xlo, int t)
{
    __shared__ float sd[60];
    __shared__ float swd[1536];
    const int b = blockIdx.x, tid = threadIdx.x;
    if (tid < 60) sd[tid] = desc[(size_t)b * (TT * ND * DS) + t * (ND * DS) + tid];
    for (int i = tid; i < 1536; i += 256) swd[i] = Wd[i];
    __syncthreads();
    const float bdv = bd[tid];
#pragma unroll
    for (int n = 0; n < ND; ++n) {
        float acc = bdv;
#pragma unroll
        for (int d = 0; d < DS; ++d) acc += sd[n * DS + d] * swd[tid * DS + d];
        const _Float16 h = (_Float16)acc;
        xhi[(size_t)b * SAW + n * 256 + tid] = h;
        xlo[(size_t)b * SAW + n * 256 + tid] = (_Float16)(acc - (float)h);
    }
}

// ---------------------------------------------------------------------------
// a[b,n] = y[b,:] . Wv[n,:] + bv[n]  -> out[b,t,n]
// ---------------------------------------------------------------------------
__global__ __launch_bounds__(256) void av_kernel(const float* __restrict__ y,
                                                 const float* __restrict__ Wv,
                                                 const float* __restrict__ bv,
                                                 float* __restrict__ out, int t)
{
    __shared__ float ys[SAW];
    __shared__ float red[ND][4];
    const int b = blockIdx.x, tid = threadIdx.x;
    for (int i = tid; i < SAW; i += 256) ys[i] = y[(size_t)b * SAW + i];
    __syncthreads();

    float pacc[ND];
#pragma unroll
    for (int n = 0; n < ND; ++n) pacc[n] = 0.f;
    for (int k = tid; k < SAW; k += 256) {
        const float yv = ys[k];
#pragma unroll
        for (int n = 0; n < ND; ++n) pacc[n] += yv * Wv[n * SAW + k];
    }
    const int lane = tid & 63, wid = tid >> 6;
#pragma unroll
    for (int n = 0; n < ND; ++n) {
        float v = pacc[n];
        for (int off = 32; off > 0; off >>= 1) v += __shfl_down(v, off, 64);
        if (lane == 0) red[n][wid] = v;
    }
    __syncthreads();
    if (tid < ND) {
        const float s = red[tid][0] + red[tid][1] + red[tid][2] + red[tid][3] + bv[tid];
        out[(size_t)b * (TT * ND) + t * ND + tid] = s;
    }
}

// ---------------------------------------------------------------------------
extern "C" void kernel_launch(void* const* d_in, const int* in_sizes, int n_in,
                              void* d_out, int out_size, void* d_ws, size_t ws_size,
                              hipStream_t stream)
{
    const float* desc = (const float*)d_in[0];
    const float* Wd   = (const float*)d_in[1];
    const float* bd   = (const float*)d_in[2];
    const float* W1   = (const float*)d_in[3];
    const float* b1   = (const float*)d_in[4];
    const float* W2   = (const float*)d_in[5];
    const float* b2   = (const float*)d_in[6];
    const float* Wv   = (const float*)d_in[7];
    const float* bv   = (const float*)d_in[8];
    const float* W_ih = (const float*)d_in[9];
    const float* W_hh = (const float*)d_in[10];
    const float* b_ih = (const float*)d_in[11];
    const float* b_hh = (const float*)d_in[12];
    float* out = (float*)d_out;

    char* ws = (char*)d_ws;
    float*     zbuf  = (float*)(ws);                    // [512][512] f32 [inp|h]
    float*     cbuf  = (float*)(ws + 1048576);          // [512][256] f32
    float*     ybuf  = (float*)(ws + 1572864);          // [512][2816] f32
    float*     gates = (float*)(ws + 7340032);          // [512][1024] f32
    float*     wcat  = (float*)(ws + 9437184);          // [1024][512] f32
    float*     bcat  = (float*)(ws + 11534336);         // [1024] f32
    _Float16*  xhi   = (_Float16*)(ws + 11538432);      // [512][2816] f16
    _Float16*  xlo   = (_Float16*)(ws + 14422016);      // [512][2816] f16
    _Float16*  w1hi  = (_Float16*)(ws + 17305600);      // [2816][2816] f16
    _Float16*  w1lo  = (_Float16*)(ws + 33165312);      // [2816][2816] f16
                                                        // end: 49,025,024 bytes

    // zero carry state (zbuf + cbuf contiguous)
    hipMemsetAsync(ws, 0, 1572864, stream);
    build_wcat<<<dim3(1024), dim3(256), 0, stream>>>(W_ih, W_hh, b_ih, b_hh, wcat, bcat);
    cvt_hilo<<<dim3(2048), dim3(256), 0, stream>>>(W1, w1hi, w1lo, SAW * SAW);

    for (int t = 0; t < TT; ++t) {
        // gates = [inp|h] . wcat^T + bcat          M=512 N=1024 K=512 (f32)
        gemm64<false><<<dim3(8, 16), dim3(256), 0, stream>>>(zbuf, 512, wcat, 512, bcat,
                                                             gates, 1024, 512);
        lstm_elem<<<dim3(512), dim3(256), 0, stream>>>(gates, cbuf, zbuf, xhi, xlo);
        emb_kernel<<<dim3(512), dim3(256), 0, stream>>>(desc, Wd, bd, xhi, xlo, t);
        // y = relu(x . W1^T + b1)                  M=512 N=2816 K=2816 (fp16x3 MFMA)
        gemm_mfma3_relu<<<dim3(8, 44), dim3(64), 0, stream>>>(xhi, xlo, SAW,
                                                              w1hi, w1lo, SAW,
                                                              b1, ybuf, SAW, SAW);
        // nxt = relu(y . W2^T + b2) -> zbuf[:,0:256]  M=512 N=256 K=2816 (f32)
        gemm64<true><<<dim3(8, 4), dim3(256), 0, stream>>>(ybuf, SAW, W2, SAW, b2,
                                                           zbuf, 512, SAW);
        av_kernel<<<dim3(512), dim3(256), 0, stream>>>(ybuf, Wv, bv, out, t);
    }
}

// Round 4
// 10064.308 us; speedup vs baseline: 3.5637x; 2.6937x over previous
//
#include <hip/hip_runtime.h>
#include <hip/hip_bf16.h>
#include <math.h>

#define TT 100
#define ND 10
#define DS 6
#define SAW 2816

typedef _Float16 half8 __attribute__((ext_vector_type(8)));
typedef float floatx4 __attribute__((ext_vector_type(4)));

// ---------------------------------------------------------------------------
// Split-fp16 3-pass MFMA GEMM: C = A.B^T (+bias)(+relu), A=Ah+Al, B=Bh+Bl.
// Fixed geometry: 256 thr = 4 waves (2x2), block tile 64x64, wave tile 32x32
// (2x2 frags of mfma_f32_16x16x32_f16), BK=32. Linear LDS [64][32] f16:
// every b128 frag read / staging write covers a contiguous 1KB block ->
// bank-conflict-free. Register prefetch of next K-tile hides global latency.
// EPI: 0 = f32 C + bias (gates)
//      1 = relu(.+bias) -> hi/lo f16 planes (W1 -> y)
//      2 = f32 partial, K-split via blockIdx.z, partial stride 512*256 (W2)
// ---------------------------------------------------------------------------
template<int EPI>
__global__ __launch_bounds__(256) void gemm_s16(
    const _Float16* __restrict__ Ah, const _Float16* __restrict__ Al, int lda,
    const _Float16* __restrict__ Bh, const _Float16* __restrict__ Bl, int ldb,
    const float* __restrict__ bias,
    float* __restrict__ Cf, _Float16* __restrict__ Chi, _Float16* __restrict__ Clo,
    int ldc, int Kloc)
{
    __shared__ alignas(16) _Float16 sAh[64 * 32];
    __shared__ alignas(16) _Float16 sAl[64 * 32];
    __shared__ alignas(16) _Float16 sBh[64 * 32];
    __shared__ alignas(16) _Float16 sBl[64 * 32];

    const int tid = threadIdx.x;
    const int w = tid >> 6, l = tid & 63;
    const int m0 = blockIdx.x * 64, n0 = blockIdx.y * 64;
    const int koff = (EPI == 2) ? blockIdx.z * Kloc : 0;

    // staging: wave w fills rows [16w,16w+16) of each plane; lane l -> 16B
    const int sr = 16 * w + (l >> 2);
    const int sc = (l & 3) * 8;
    const int sidx = sr * 32 + sc;
    const _Float16* gAh = Ah + (size_t)(m0 + sr) * lda + koff + sc;
    const _Float16* gAl = Al + (size_t)(m0 + sr) * lda + koff + sc;
    const _Float16* gBh = Bh + (size_t)(n0 + sr) * ldb + koff + sc;
    const _Float16* gBl = Bl + (size_t)(n0 + sr) * ldb + koff + sc;

    // wave sub-tile: rows mw.., cols nw..
    const int mw = (w >> 1) * 32, nw = (w & 1) * 32;
    const int fr = l & 15, fk = (l >> 4) * 8;   // frag row / k-chunk

    floatx4 acc[2][2];
    const floatx4 z = {0.f, 0.f, 0.f, 0.f};
#pragma unroll
    for (int i = 0; i < 2; ++i)
#pragma unroll
        for (int j = 0; j < 2; ++j) acc[i][j] = z;

    half8 rAh = *(const half8*)gAh;
    half8 rAl = *(const half8*)gAl;
    half8 rBh = *(const half8*)gBh;
    half8 rBl = *(const half8*)gBl;

    for (int kt = 0; kt < Kloc; kt += 32) {
        *(half8*)&sAh[sidx] = rAh;
        *(half8*)&sAl[sidx] = rAl;
        *(half8*)&sBh[sidx] = rBh;
        *(half8*)&sBl[sidx] = rBl;
        __syncthreads();
        if (kt + 32 < Kloc) {           // prefetch next K-tile into regs
            rAh = *(const half8*)(gAh + kt + 32);
            rAl = *(const half8*)(gAl + kt + 32);
            rBh = *(const half8*)(gBh + kt + 32);
            rBl = *(const half8*)(gBl + kt + 32);
        }
        half8 aH[2], aL[2], bH[2], bL[2];
#pragma unroll
        for (int mf = 0; mf < 2; ++mf) {
            const int ro = (mw + mf * 16 + fr) * 32 + fk;
            aH[mf] = *(const half8*)&sAh[ro];
            aL[mf] = *(const half8*)&sAl[ro];
        }
#pragma unroll
        for (int nf = 0; nf < 2; ++nf) {
            const int ro = (nw + nf * 16 + fr) * 32 + fk;
            bH[nf] = *(const half8*)&sBh[ro];
            bL[nf] = *(const half8*)&sBl[ro];
        }
#pragma unroll
        for (int mf = 0; mf < 2; ++mf)
#pragma unroll
            for (int nf = 0; nf < 2; ++nf)
                acc[mf][nf] = __builtin_amdgcn_mfma_f32_16x16x32_f16(aH[mf], bH[nf], acc[mf][nf], 0, 0, 0);
#pragma unroll
        for (int mf = 0; mf < 2; ++mf)
#pragma unroll
            for (int nf = 0; nf < 2; ++nf)
                acc[mf][nf] = __builtin_amdgcn_mfma_f32_16x16x32_f16(aH[mf], bL[nf], acc[mf][nf], 0, 0, 0);
#pragma unroll
        for (int mf = 0; mf < 2; ++mf)
#pragma unroll
            for (int nf = 0; nf < 2; ++nf)
                acc[mf][nf] = __builtin_amdgcn_mfma_f32_16x16x32_f16(aL[mf], bH[nf], acc[mf][nf], 0, 0, 0);
        __syncthreads();
    }

    // C/D layout: col = l&15, row = 4*(l>>4) + r
    const int cr = (l >> 4) * 4, cc = l & 15;
#pragma unroll
    for (int nf = 0; nf < 2; ++nf) {
        const int col = n0 + nw + nf * 16 + cc;
        float bv = 0.f;
        if constexpr (EPI != 2) bv = bias[col];
#pragma unroll
        for (int mf = 0; mf < 2; ++mf) {
            const int row = m0 + mw + mf * 16 + cr;
#pragma unroll
            for (int r = 0; r < 4; ++r) {
                float v = acc[mf][nf][r] + bv;
                if constexpr (EPI == 0) {
                    Cf[(size_t)(row + r) * ldc + col] = v;
                } else if constexpr (EPI == 1) {
                    v = v > 0.f ? v : 0.f;
                    const _Float16 h = (_Float16)v;
                    Chi[(size_t)(row + r) * ldc + col] = h;
                    Clo[(size_t)(row + r) * ldc + col] = (_Float16)(v - (float)h);
                } else {
                    Cf[(size_t)blockIdx.z * (512 * 256) + (size_t)(row + r) * ldc + col] = v;
                }
            }
        }
    }
}

// ---------------------------------------------------------------------------
// fused LSTM elementwise + FrameAttention embedding (one block per batch row)
// ---------------------------------------------------------------------------
__global__ __launch_bounds__(256) void lstm_emb(
    const float* __restrict__ gates, float* __restrict__ cbuf,
    _Float16* __restrict__ zhi, _Float16* __restrict__ zlo,
    _Float16* __restrict__ xhi, _Float16* __restrict__ xlo,
    const float* __restrict__ desc, const float* __restrict__ Wd,
    const float* __restrict__ bd, int t)
{
    __shared__ float sd[60];
    __shared__ float swd[1536];
    const int b = blockIdx.x, k = threadIdx.x;
    if (k < 60) sd[k] = desc[(size_t)b * (TT * ND * DS) + t * (ND * DS) + k];
    for (int i = k; i < 1536; i += 256) swd[i] = Wd[i];

    // LSTM cell (gate order i,f,g,o)
    const float gi = gates[b * 1024 + k];
    const float gf = gates[b * 1024 + 256 + k];
    const float gg = gates[b * 1024 + 512 + k];
    const float go = gates[b * 1024 + 768 + k];
    const float si = 1.f / (1.f + expf(-gi));
    const float sf = 1.f / (1.f + expf(-gf));
    const float so = 1.f / (1.f + expf(-go));
    float cv = cbuf[b * 256 + k];
    cv = sf * cv + si * tanhf(gg);
    const float hv = so * tanhf(cv);
    cbuf[b * 256 + k] = cv;
    {
        const _Float16 h = (_Float16)hv;
        const _Float16 lo = (_Float16)(hv - (float)h);
        zhi[b * 512 + 256 + k] = h;   zlo[b * 512 + 256 + k] = lo;
        xhi[(size_t)b * SAW + 2560 + k] = h;
        xlo[(size_t)b * SAW + 2560 + k] = lo;
    }
    __syncthreads();

    // embedding: x[b, n*256+k] = bd[k] + sum_d desc[b,t,n,d]*Wd[k,d]
    const float bdv = bd[k];
#pragma unroll
    for (int n = 0; n < ND; ++n) {
        float a = bdv;
#pragma unroll
        for (int d = 0; d < DS; ++d) a += sd[n * DS + d] * swd[k * DS + d];
        const _Float16 h = (_Float16)a;
        xhi[(size_t)b * SAW + n * 256 + k] = h;
        xlo[(size_t)b * SAW + n * 256 + k] = (_Float16)(a - (float)h);
    }
}

// ---------------------------------------------------------------------------
// fused: a = y.Wv^T + bv -> out[b,t,:]  AND  W2 K-split partial reduce ->
// inp_next = relu(sum + b2) -> zhi/zlo[:, 0:256]
// ---------------------------------------------------------------------------
__global__ __launch_bounds__(256) void av_w2fin(
    const _Float16* __restrict__ yhi, const _Float16* __restrict__ ylo,
    const float* __restrict__ Wv, const float* __restrict__ bv,
    const float* __restrict__ pbuf, const float* __restrict__ b2,
    _Float16* __restrict__ zhi, _Float16* __restrict__ zlo,
    float* __restrict__ out, int t)
{
    __shared__ float ys[SAW];
    __shared__ float red[ND][4];
    const int b = blockIdx.x, tid = threadIdx.x;
    for (int i = tid; i < SAW; i += 256)
        ys[i] = (float)yhi[(size_t)b * SAW + i] + (float)ylo[(size_t)b * SAW + i];
    __syncthreads();

    float pacc[ND];
#pragma unroll
    for (int n = 0; n < ND; ++n) pacc[n] = 0.f;
    for (int kk = tid; kk < SAW; kk += 256) {
        const float yv = ys[kk];
#pragma unroll
        for (int n = 0; n < ND; ++n) pacc[n] += yv * Wv[n * SAW + kk];
    }
    const int lane = tid & 63, wid = tid >> 6;
#pragma unroll
    for (int n = 0; n < ND; ++n) {
        float v = pacc[n];
        for (int off = 32; off > 0; off >>= 1) v += __shfl_down(v, off, 64);
        if (lane == 0) red[n][wid] = v;
    }
    // W2 finish: sum 4 K-split partials, bias, relu, hi/lo split
    {
        const int j = tid;
        float s = b2[j];
#pragma unroll
        for (int kc = 0; kc < 4; ++kc) s += pbuf[kc * 131072 + b * 256 + j];
        s = s > 0.f ? s : 0.f;
        const _Float16 h = (_Float16)s;
        zhi[b * 512 + j] = h;
        zlo[b * 512 + j] = (_Float16)(s - (float)h);
    }
    __syncthreads();
    if (tid < ND) {
        const float s = red[tid][0] + red[tid][1] + red[tid][2] + red[tid][3] + bv[tid];
        out[(size_t)b * (TT * ND) + t * ND + tid] = s;
    }
}

// ---------------------------------------------------------------------------
// one-time prep: concat+split LSTM weights; generic f32 -> hi/lo split
// ---------------------------------------------------------------------------
__global__ void build_wcat_split(const float* __restrict__ W_ih, const float* __restrict__ W_hh,
                                 const float* __restrict__ b_ih, const float* __restrict__ b_hh,
                                 _Float16* __restrict__ wchi, _Float16* __restrict__ wclo,
                                 float* __restrict__ bcat)
{
    const int j = blockIdx.x, k = threadIdx.x;
    const float v1 = W_ih[j * 256 + k];
    const _Float16 h1 = (_Float16)v1;
    wchi[j * 512 + k] = h1;
    wclo[j * 512 + k] = (_Float16)(v1 - (float)h1);
    const float v2 = W_hh[j * 256 + k];
    const _Float16 h2 = (_Float16)v2;
    wchi[j * 512 + 256 + k] = h2;
    wclo[j * 512 + 256 + k] = (_Float16)(v2 - (float)h2);
    if (k == 0) bcat[j] = b_ih[j] + b_hh[j];
}

__global__ __launch_bounds__(256) void cvt_hilo(const float* __restrict__ src,
                                                _Float16* __restrict__ hi,
                                                _Float16* __restrict__ lo, int n)
{
    int i = blockIdx.x * 256 + threadIdx.x;
    const int stride = gridDim.x * 256;
    for (; i < n; i += stride) {
        const float v = src[i];
        const _Float16 h = (_Float16)v;
        hi[i] = h;
        lo[i] = (_Float16)(v - (float)h);
    }
}

// ---------------------------------------------------------------------------
extern "C" void kernel_launch(void* const* d_in, const int* in_sizes, int n_in,
                              void* d_out, int out_size, void* d_ws, size_t ws_size,
                              hipStream_t stream)
{
    const float* desc = (const float*)d_in[0];
    const float* Wd   = (const float*)d_in[1];
    const float* bd   = (const float*)d_in[2];
    const float* W1   = (const float*)d_in[3];
    const float* b1   = (const float*)d_in[4];
    const float* W2   = (const float*)d_in[5];
    const float* b2   = (const float*)d_in[6];
    const float* Wv   = (const float*)d_in[7];
    const float* bv   = (const float*)d_in[8];
    const float* W_ih = (const float*)d_in[9];
    const float* W_hh = (const float*)d_in[10];
    const float* b_ih = (const float*)d_in[11];
    const float* b_hh = (const float*)d_in[12];
    float* out = (float*)d_out;

    char* ws = (char*)d_ws;
    // state
    _Float16* zhi  = (_Float16*)(ws);                  // [512][512]  inp|h hi
    _Float16* zlo  = (_Float16*)(ws + 524288);         // [512][512]  lo
    float*    cbuf = (float*)(ws + 1048576);           // [512][256]  f32
    // x region (pbuf aliases its head: lifetimes disjoint — pbuf: W2(t)->av(t),
    // x: lstm_emb(t)->W1(t))
    _Float16* xhi  = (_Float16*)(ws + 1572864);        // [512][2816]
    _Float16* xlo  = (_Float16*)(ws + 4456448);        // [512][2816]
    float*    pbuf = (float*)(ws + 1572864);           // [4][512][256] f32 partials
    // y region (gates aliases its head: gates: gg(t)->lstm(t), y: W1(t)->av(t))
    _Float16* yhi  = (_Float16*)(ws + 7340032);        // [512][2816]
    _Float16* ylo  = (_Float16*)(ws + 10223616);       // [512][2816]
    float*    gates= (float*)(ws + 7340032);           // [512][1024] f32
    // weights (persistent)
    _Float16* wchi = (_Float16*)(ws + 13107200);       // [1024][512]
    _Float16* wclo = (_Float16*)(ws + 14155776);
    _Float16* w2hi = (_Float16*)(ws + 15204352);       // [256][2816]
    _Float16* w2lo = (_Float16*)(ws + 16646144);
    _Float16* w1hi = (_Float16*)(ws + 18087936);       // [2816][2816]
    _Float16* w1lo = (_Float16*)(ws + 33947648);
    float*    bcat = (float*)(ws + 49807360);          // [1024]
    // total 49,811,456 bytes

    hipMemsetAsync(ws, 0, 1572864, stream);            // zero zhi, zlo, cbuf
    build_wcat_split<<<dim3(1024), dim3(256), 0, stream>>>(W_ih, W_hh, b_ih, b_hh,
                                                           wchi, wclo, bcat);
    cvt_hilo<<<dim3(4096), dim3(256), 0, stream>>>(W1, w1hi, w1lo, SAW * SAW);
    cvt_hilo<<<dim3(704), dim3(256), 0, stream>>>(W2, w2hi, w2lo, 256 * SAW);

    for (int t = 0; t < TT; ++t) {
        // gates = z . wcat^T + bcat            M=512 N=1024 K=512
        gemm_s16<0><<<dim3(8, 16), dim3(256), 0, stream>>>(
            zhi, zlo, 512, wchi, wclo, 512, bcat, gates, nullptr, nullptr, 1024, 512);
        lstm_emb<<<dim3(512), dim3(256), 0, stream>>>(gates, cbuf, zhi, zlo, xhi, xlo,
                                                      desc, Wd, bd, t);
        // y = relu(x . W1^T + b1) -> hi/lo     M=512 N=2816 K=2816
        gemm_s16<1><<<dim3(8, 44), dim3(256), 0, stream>>>(
            xhi, xlo, SAW, w1hi, w1lo, SAW, b1, nullptr, yhi, ylo, SAW, SAW);
        // W2 partials (K-split x4)             M=512 N=256 K=4x704
        gemm_s16<2><<<dim3(8, 4, 4), dim3(256), 0, stream>>>(
            yhi, ylo, SAW, w2hi, w2lo, SAW, nullptr, pbuf, nullptr, nullptr, 256, 704);
        // out[t] = y.Wv^T + bv ; inp_next = relu(sum pbuf + b2) -> z[:, :256]
        av_w2fin<<<dim3(512), dim3(256), 0, stream>>>(yhi, ylo, Wv, bv, pbuf, b2,
                                                      zhi, zlo, out, t);
    }
}

// Round 6
// 8737.976 us; speedup vs baseline: 4.1046x; 1.1518x over previous
//
#include <hip/hip_runtime.h>
#include <hip/hip_bf16.h>
#include <math.h>

#define TT 100
#define ND 10
#define DS 6
#define SAW 2816

typedef _Float16 half8 __attribute__((ext_vector_type(8)));
typedef float floatx4 __attribute__((ext_vector_type(4)));

__device__ __forceinline__ void gload_lds16(const _Float16* g, _Float16* l) {
    __builtin_amdgcn_global_load_lds((const __attribute__((address_space(1))) void*)g,
                                     (__attribute__((address_space(3))) void*)l, 16, 0, 0);
}

// ---------------------------------------------------------------------------
// Split-fp16 3-pass MFMA GEMM, big tile: Cpart[z] = A.B^T (raw f32 partial).
// Block 128x128, 4 waves (2x2), wave tile 64x64 = 4x4 frags of 16x16x32_f16.
// BK=32. K-split via blockIdx.z (Kloc per z). Staging via global_load_lds
// width-16: wave w stages plane w (0=Ah,1=Al,2=Bh,3=Bl), 8 chunks of 1KB;
// LDS chunk base + lane*16B == row-major [128][32] f16 plane (verified:
// (l>>2)*64 + (l&3)*16 == l*16). Frag ds_read_b128s tile contiguous 1KB
// blocks per wave -> bank-conflict-free.
// ---------------------------------------------------------------------------
__global__ __launch_bounds__(256) void gemm_big(
    const _Float16* __restrict__ Ah, const _Float16* __restrict__ Al, int lda,
    const _Float16* __restrict__ Bh, const _Float16* __restrict__ Bl, int ldb,
    float* __restrict__ Cpart, size_t zstride, int ldc, int Kloc)
{
    __shared__ alignas(16) _Float16 lds[4 * 128 * 32];   // planes: Ah,Al,Bh,Bl

    const int tid = threadIdx.x;
    const int w = tid >> 6, l = tid & 63;
    const int m0 = blockIdx.x * 128, n0 = blockIdx.y * 128;
    const int koff = blockIdx.z * Kloc;

    // staging source for this thread's wave-plane
    const _Float16* plane_src;
    int plane_ld;
    if (w == 0)      { plane_src = Ah + (size_t)m0 * lda; plane_ld = lda; }
    else if (w == 1) { plane_src = Al + (size_t)m0 * lda; plane_ld = lda; }
    else if (w == 2) { plane_src = Bh + (size_t)n0 * ldb; plane_ld = ldb; }
    else             { plane_src = Bl + (size_t)n0 * ldb; plane_ld = ldb; }
    const int srow_in_chunk = l >> 2;          // 0..15
    const int scol = (l & 3) * 8;              // f16 col within BK=32
    _Float16* const lds_plane = lds + w * 4096;

    // wave output sub-tile
    const int wr = (w >> 1) * 64, wc = (w & 1) * 64;
    const int fr = l & 15, fk = (l >> 4) * 8;

    floatx4 acc[4][4];
    const floatx4 z4 = {0.f, 0.f, 0.f, 0.f};
#pragma unroll
    for (int i = 0; i < 4; ++i)
#pragma unroll
        for (int j = 0; j < 4; ++j) acc[i][j] = z4;

    for (int kt = 0; kt < Kloc; kt += 32) {
        __syncthreads();   // previous tile's reads complete before overwrite
#pragma unroll
        for (int i = 0; i < 8; ++i) {
            const int row = i * 16 + srow_in_chunk;
            gload_lds16(plane_src + (size_t)row * plane_ld + koff + kt + scol,
                        lds_plane + i * 512);
        }
        __syncthreads();   // implicit vmcnt(0) drain -> LDS tile ready

        half8 aH[4], aL[4], bH[4], bL[4];
#pragma unroll
        for (int f = 0; f < 4; ++f) {
            const int ra = (wr + f * 16 + fr) * 32 + fk;
            const int rb = (wc + f * 16 + fr) * 32 + fk;
            aH[f] = *(const half8*)&lds[ra];
            aL[f] = *(const half8*)&lds[4096 + ra];
            bH[f] = *(const half8*)&lds[8192 + rb];
            bL[f] = *(const half8*)&lds[12288 + rb];
        }
#pragma unroll
        for (int mf = 0; mf < 4; ++mf)
#pragma unroll
            for (int nf = 0; nf < 4; ++nf)
                acc[mf][nf] = __builtin_amdgcn_mfma_f32_16x16x32_f16(aH[mf], bH[nf], acc[mf][nf], 0, 0, 0);
#pragma unroll
        for (int mf = 0; mf < 4; ++mf)
#pragma unroll
            for (int nf = 0; nf < 4; ++nf)
                acc[mf][nf] = __builtin_amdgcn_mfma_f32_16x16x32_f16(aH[mf], bL[nf], acc[mf][nf], 0, 0, 0);
#pragma unroll
        for (int mf = 0; mf < 4; ++mf)
#pragma unroll
            for (int nf = 0; nf < 4; ++nf)
                acc[mf][nf] = __builtin_amdgcn_mfma_f32_16x16x32_f16(aL[mf], bH[nf], acc[mf][nf], 0, 0, 0);
    }

    // C/D layout: col = l&15, row = 4*(l>>4) + r
    float* const Cz = Cpart + (size_t)blockIdx.z * zstride;
    const int cr = (l >> 4) * 4, cc = l & 15;
#pragma unroll
    for (int mf = 0; mf < 4; ++mf) {
        const int row = m0 + wr + mf * 16 + cr;
#pragma unroll
        for (int nf = 0; nf < 4; ++nf) {
            const int col = n0 + wc + nf * 16 + cc;
#pragma unroll
            for (int r = 0; r < 4; ++r)
                Cz[(size_t)(row + r) * ldc + col] = acc[mf][nf][r];
        }
    }
}

// ---------------------------------------------------------------------------
// Old 64x64 split-fp16 GEMM, K-split partial epilogue (W2 only).
// ---------------------------------------------------------------------------
__global__ __launch_bounds__(256) void gemm_s16_part(
    const _Float16* __restrict__ Ah, const _Float16* __restrict__ Al, int lda,
    const _Float16* __restrict__ Bh, const _Float16* __restrict__ Bl, int ldb,
    float* __restrict__ Cf, int ldc, int Kloc)
{
    __shared__ alignas(16) _Float16 sAh[64 * 32];
    __shared__ alignas(16) _Float16 sAl[64 * 32];
    __shared__ alignas(16) _Float16 sBh[64 * 32];
    __shared__ alignas(16) _Float16 sBl[64 * 32];

    const int tid = threadIdx.x;
    const int w = tid >> 6, l = tid & 63;
    const int m0 = blockIdx.x * 64, n0 = blockIdx.y * 64;
    const int koff = blockIdx.z * Kloc;

    const int sr = 16 * w + (l >> 2);
    const int sc = (l & 3) * 8;
    const int sidx = sr * 32 + sc;
    const _Float16* gAh = Ah + (size_t)(m0 + sr) * lda + koff + sc;
    const _Float16* gAl = Al + (size_t)(m0 + sr) * lda + koff + sc;
    const _Float16* gBh = Bh + (size_t)(n0 + sr) * ldb + koff + sc;
    const _Float16* gBl = Bl + (size_t)(n0 + sr) * ldb + koff + sc;

    const int mw = (w >> 1) * 32, nw = (w & 1) * 32;
    const int fr = l & 15, fk = (l >> 4) * 8;

    floatx4 acc[2][2];
    const floatx4 z = {0.f, 0.f, 0.f, 0.f};
#pragma unroll
    for (int i = 0; i < 2; ++i)
#pragma unroll
        for (int j = 0; j < 2; ++j) acc[i][j] = z;

    half8 rAh = *(const half8*)gAh;
    half8 rAl = *(const half8*)gAl;
    half8 rBh = *(const half8*)gBh;
    half8 rBl = *(const half8*)gBl;

    for (int kt = 0; kt < Kloc; kt += 32) {
        *(half8*)&sAh[sidx] = rAh;
        *(half8*)&sAl[sidx] = rAl;
        *(half8*)&sBh[sidx] = rBh;
        *(half8*)&sBl[sidx] = rBl;
        __syncthreads();
        if (kt + 32 < Kloc) {
            rAh = *(const half8*)(gAh + kt + 32);
            rAl = *(const half8*)(gAl + kt + 32);
            rBh = *(const half8*)(gBh + kt + 32);
            rBl = *(const half8*)(gBl + kt + 32);
        }
        half8 aH[2], aL[2], bH[2], bL[2];
#pragma unroll
        for (int mf = 0; mf < 2; ++mf) {
            const int ro = (mw + mf * 16 + fr) * 32 + fk;
            aH[mf] = *(const half8*)&sAh[ro];
            aL[mf] = *(const half8*)&sAl[ro];
        }
#pragma unroll
        for (int nf = 0; nf < 2; ++nf) {
            const int ro = (nw + nf * 16 + fr) * 32 + fk;
            bH[nf] = *(const half8*)&sBh[ro];
            bL[nf] = *(const half8*)&sBl[ro];
        }
#pragma unroll
        for (int mf = 0; mf < 2; ++mf)
#pragma unroll
            for (int nf = 0; nf < 2; ++nf)
                acc[mf][nf] = __builtin_amdgcn_mfma_f32_16x16x32_f16(aH[mf], bH[nf], acc[mf][nf], 0, 0, 0);
#pragma unroll
        for (int mf = 0; mf < 2; ++mf)
#pragma unroll
            for (int nf = 0; nf < 2; ++nf)
                acc[mf][nf] = __builtin_amdgcn_mfma_f32_16x16x32_f16(aH[mf], bL[nf], acc[mf][nf], 0, 0, 0);
#pragma unroll
        for (int mf = 0; mf < 2; ++mf)
#pragma unroll
            for (int nf = 0; nf < 2; ++nf)
                acc[mf][nf] = __builtin_amdgcn_mfma_f32_16x16x32_f16(aL[mf], bH[nf], acc[mf][nf], 0, 0, 0);
        __syncthreads();
    }

    const int cr = (l >> 4) * 4, cc = l & 15;
#pragma unroll
    for (int nf = 0; nf < 2; ++nf) {
        const int col = n0 + nw + nf * 16 + cc;
#pragma unroll
        for (int mf = 0; mf < 2; ++mf) {
            const int row = m0 + mw + mf * 16 + cr;
#pragma unroll
            for (int r = 0; r < 4; ++r)
                Cf[(size_t)blockIdx.z * (512 * 256) + (size_t)(row + r) * ldc + col]
                    = acc[mf][nf][r];
        }
    }
}

// ---------------------------------------------------------------------------
// y = relu(sum_z pbufY[z] + b1) -> hi/lo f16 planes
// ---------------------------------------------------------------------------
__global__ __launch_bounds__(256) void yred(const float* __restrict__ pbufY,
                                            const float* __restrict__ b1,
                                            _Float16* __restrict__ yhi,
                                            _Float16* __restrict__ ylo)
{
    const int b = blockIdx.x, tid = threadIdx.x;
    for (int i = tid; i < SAW; i += 256) {
        float s = b1[i];
#pragma unroll
        for (int z = 0; z < 4; ++z) s += pbufY[(size_t)z * 1441792 + (size_t)b * SAW + i];
        s = s > 0.f ? s : 0.f;
        const _Float16 h = (_Float16)s;
        yhi[(size_t)b * SAW + i] = h;
        ylo[(size_t)b * SAW + i] = (_Float16)(s - (float)h);
    }
}

// ---------------------------------------------------------------------------
// fused LSTM elementwise (sums 4 gate partials + bias) + embedding
// ---------------------------------------------------------------------------
__global__ __launch_bounds__(256) void lstm_emb(
    const float* __restrict__ gpart, const float* __restrict__ b_ih,
    const float* __restrict__ b_hh, float* __restrict__ cbuf,
    _Float16* __restrict__ zhi, _Float16* __restrict__ zlo,
    _Float16* __restrict__ xhi, _Float16* __restrict__ xlo,
    const float* __restrict__ desc, const float* __restrict__ Wd,
    const float* __restrict__ bd, int t)
{
    __shared__ float sd[60];
    __shared__ float swd[1536];
    const int b = blockIdx.x, k = threadIdx.x;
    if (k < 60) sd[k] = desc[(size_t)b * (TT * ND * DS) + t * (ND * DS) + k];
    for (int i = k; i < 1536; i += 256) swd[i] = Wd[i];

    float gate[4];
#pragma unroll
    for (int g = 0; g < 4; ++g) {
        const int idx = g * 256 + k;
        float s = b_ih[idx] + b_hh[idx];
#pragma unroll
        for (int z = 0; z < 4; ++z) s += gpart[z * 524288 + b * 1024 + idx];
        gate[g] = s;
    }
    const float si = 1.f / (1.f + expf(-gate[0]));
    const float sf = 1.f / (1.f + expf(-gate[1]));
    const float so = 1.f / (1.f + expf(-gate[3]));
    float cv = cbuf[b * 256 + k];
    cv = sf * cv + si * tanhf(gate[2]);
    const float hv = so * tanhf(cv);
    cbuf[b * 256 + k] = cv;
    {
        const _Float16 h = (_Float16)hv;
        const _Float16 lo = (_Float16)(hv - (float)h);
        zhi[b * 512 + 256 + k] = h;   zlo[b * 512 + 256 + k] = lo;
        xhi[(size_t)b * SAW + 2560 + k] = h;
        xlo[(size_t)b * SAW + 2560 + k] = lo;
    }
    __syncthreads();

    const float bdv = bd[k];
#pragma unroll
    for (int n = 0; n < ND; ++n) {
        float a = bdv;
#pragma unroll
        for (int d = 0; d < DS; ++d) a += sd[n * DS + d] * swd[k * DS + d];
        const _Float16 h = (_Float16)a;
        xhi[(size_t)b * SAW + n * 256 + k] = h;
        xlo[(size_t)b * SAW + n * 256 + k] = (_Float16)(a - (float)h);
    }
}

// ---------------------------------------------------------------------------
// fused: a = y.Wv^T + bv -> out[b,t,:]  AND  W2 partial reduce -> z[:, :256]
// ---------------------------------------------------------------------------
__global__ __launch_bounds__(256) void av_w2fin(
    const _Float16* __restrict__ yhi, const _Float16* __restrict__ ylo,
    const float* __restrict__ Wv, const float* __restrict__ bv,
    const float* __restrict__ pbuf, const float* __restrict__ b2,
    _Float16* __restrict__ zhi, _Float16* __restrict__ zlo,
    float* __restrict__ out, int t)
{
    __shared__ float ys[SAW];
    __shared__ float red[ND][4];
    const int b = blockIdx.x, tid = threadIdx.x;
    for (int i = tid; i < SAW; i += 256)
        ys[i] = (float)yhi[(size_t)b * SAW + i] + (float)ylo[(size_t)b * SAW + i];
    __syncthreads();

    float pacc[ND];
#pragma unroll
    for (int n = 0; n < ND; ++n) pacc[n] = 0.f;
    for (int kk = tid; kk < SAW; kk += 256) {
        const float yv = ys[kk];
#pragma unroll
        for (int n = 0; n < ND; ++n) pacc[n] += yv * Wv[n * SAW + kk];
    }
    const int lane = tid & 63, wid = tid >> 6;
#pragma unroll
    for (int n = 0; n < ND; ++n) {
        float v = pacc[n];
        for (int off = 32; off > 0; off >>= 1) v += __shfl_down(v, off, 64);
        if (lane == 0) red[n][wid] = v;
    }
    {
        const int j = tid;
        float s = b2[j];
#pragma unroll
        for (int kc = 0; kc < 4; ++kc) s += pbuf[kc * 131072 + b * 256 + j];
        s = s > 0.f ? s : 0.f;
        const _Float16 h = (_Float16)s;
        zhi[b * 512 + j] = h;
        zlo[b * 512 + j] = (_Float16)(s - (float)h);
    }
    __syncthreads();
    if (tid < ND) {
        const float s = red[tid][0] + red[tid][1] + red[tid][2] + red[tid][3] + bv[tid];
        out[(size_t)b * (TT * ND) + t * ND + tid] = s;
    }
}

// ---------------------------------------------------------------------------
// one-time prep
// ---------------------------------------------------------------------------
__global__ void build_wcat_split(const float* __restrict__ W_ih, const float* __restrict__ W_hh,
                                 _Float16* __restrict__ wchi, _Float16* __restrict__ wclo)
{
    const int j = blockIdx.x, k = threadIdx.x;
    const float v1 = W_ih[j * 256 + k];
    const _Float16 h1 = (_Float16)v1;
    wchi[j * 512 + k] = h1;
    wclo[j * 512 + k] = (_Float16)(v1 - (float)h1);
    const float v2 = W_hh[j * 256 + k];
    const _Float16 h2 = (_Float16)v2;
    wchi[j * 512 + 256 + k] = h2;
    wclo[j * 512 + 256 + k] = (_Float16)(v2 - (float)h2);
}

__global__ __launch_bounds__(256) void cvt_hilo(const float* __restrict__ src,
                                                _Float16* __restrict__ hi,
                                                _Float16* __restrict__ lo, int n)
{
    int i = blockIdx.x * 256 + threadIdx.x;
    const int stride = gridDim.x * 256;
    for (; i < n; i += stride) {
        const float v = src[i];
        const _Float16 h = (_Float16)v;
        hi[i] = h;
        lo[i] = (_Float16)(v - (float)h);
    }
}

// ---------------------------------------------------------------------------
extern "C" void kernel_launch(void* const* d_in, const int* in_sizes, int n_in,
                              void* d_out, int out_size, void* d_ws, size_t ws_size,
                              hipStream_t stream)
{
    const float* desc = (const float*)d_in[0];
    const float* Wd   = (const float*)d_in[1];
    const float* bd   = (const float*)d_in[2];
    const float* W1   = (const float*)d_in[3];
    const float* b1   = (const float*)d_in[4];
    const float* W2   = (const float*)d_in[5];
    const float* b2   = (const float*)d_in[6];
    const float* Wv   = (const float*)d_in[7];
    const float* bv   = (const float*)d_in[8];
    const float* W_ih = (const float*)d_in[9];
    const float* W_hh = (const float*)d_in[10];
    const float* b_ih = (const float*)d_in[11];
    const float* b_hh = (const float*)d_in[12];
    float* out = (float*)d_out;

    char* ws = (char*)d_ws;
    // persistent state
    _Float16* zhi  = (_Float16*)(ws);                  // [512][512]
    _Float16* zlo  = (_Float16*)(ws + 524288);
    float*    cbuf = (float*)(ws + 1048576);           // [512][256] f32
    // X region: x (lstm_emb->W1) aliases y (yred->av) — lifetimes disjoint
    _Float16* xhi  = (_Float16*)(ws + 1572864);        // [512][2816]
    _Float16* xlo  = (_Float16*)(ws + 4456448);
    _Float16* yhi  = xhi;
    _Float16* ylo  = xlo;
    // R region (23068672 B): gpart (gates->lstm_emb), pbufY (W1->yred),
    // pbufW2 (W2->av) — sequential lifetimes, all alias base R
    float*    gpart = (float*)(ws + 7340032);          // [4][512][1024]
    float*    pbufY = (float*)(ws + 7340032);          // [4][512][2816]
    float*    pbufW2= (float*)(ws + 7340032);          // [4][512][256]
    // weights (persistent)
    _Float16* wchi = (_Float16*)(ws + 30408704);       // [1024][512]
    _Float16* wclo = (_Float16*)(ws + 31457280);
    _Float16* w2hi = (_Float16*)(ws + 32505856);       // [256][2816]
    _Float16* w2lo = (_Float16*)(ws + 33947648);
    _Float16* w1hi = (_Float16*)(ws + 35389440);       // [2816][2816]
    _Float16* w1lo = (_Float16*)(ws + 51249152);
    // end = 67108864 B = 64 MiB exactly

    hipMemsetAsync(ws, 0, 1572864, stream);            // zero zhi, zlo, cbuf
    build_wcat_split<<<dim3(1024), dim3(256), 0, stream>>>(W_ih, W_hh, wchi, wclo);
    cvt_hilo<<<dim3(4096), dim3(256), 0, stream>>>(W1, w1hi, w1lo, SAW * SAW);
    cvt_hilo<<<dim3(704), dim3(256), 0, stream>>>(W2, w2hi, w2lo, 256 * SAW);

    for (int t = 0; t < TT; ++t) {
        // gates partials: z[512x512] . wcat^T[1024x512], K-split x4 (Kloc=128)
        gemm_big<<<dim3(4, 8, 4), dim3(256), 0, stream>>>(
            zhi, zlo, 512, wchi, wclo, 512, gpart, 524288, 1024, 128);
        lstm_emb<<<dim3(512), dim3(256), 0, stream>>>(gpart, b_ih, b_hh, cbuf,
                                                      zhi, zlo, xhi, xlo,
                                                      desc, Wd, bd, t);
        // W1 partials: x . W1^T, M=512 N=2816, K-split x4 (Kloc=704)
        gemm_big<<<dim3(4, 22, 4), dim3(256), 0, stream>>>(
            xhi, xlo, SAW, w1hi, w1lo, SAW, pbufY, 1441792, SAW, 704);
        // y = relu(sum + b1) -> hi/lo (X region)
        yred<<<dim3(512), dim3(256), 0, stream>>>(pbufY, b1, yhi, ylo);
        // W2 partials (K-split x4, 64x64 template)
        gemm_s16_part<<<dim3(8, 4, 4), dim3(256), 0, stream>>>(
            yhi, ylo, SAW, w2hi, w2lo, SAW, pbufW2, 256, 704);
        // out[t] = y.Wv^T + bv ; inp_next = relu(sum pbufW2 + b2) -> z[:, :256]
        av_w2fin<<<dim3(512), dim3(256), 0, stream>>>(yhi, ylo, Wv, bv, pbufW2, b2,
                                                      zhi, zlo, out, t);
    }
}